// Round 2
// baseline (892.050 us; speedup 1.0000x reference)
//
#include <hip/hip_runtime.h>
#include <math.h>

#define NUM_IN 1024
#define TILE_R 16
#define NB_MAX 256

using bf16x8 = __attribute__((ext_vector_type(8))) short;
using f32x4  = __attribute__((ext_vector_type(4))) float;

__device__ __forceinline__ unsigned int f2bf1(float f) {
  unsigned int u = __float_as_uint(f);
  return (u + 0x7fffu + ((u >> 16) & 1u)) >> 16;   // RNE f32 -> bf16
}
__device__ __forceinline__ unsigned int pk2(float a, float b) {
  return f2bf1(a) | (f2bf1(b) << 16);
}
__device__ __forceinline__ float bf2f(unsigned int s) {
  return __uint_as_float(s << 16);
}

// barrier that drains LDS only (NOT vmcnt) so producers' in-flight global
// loads are never serialized by mid-round syncs
#define BARX() do { \
  __builtin_amdgcn_sched_barrier(0); \
  asm volatile("s_waitcnt lgkmcnt(0)" ::: "memory"); \
  __builtin_amdgcn_s_barrier(); \
  __builtin_amdgcn_sched_barrier(0); \
} while (0)

// Block: 768 threads = 12 waves. Waves 0-7 consumers (nt = w&3, khalf = w>>2),
// waves 8-11 producers (stage 16-row x-tile -> swizzled bf16 LDS).
__global__ __launch_bounds__(768, 1) void ga_main(
    const float* __restrict__ x,
    const float* __restrict__ Vw, const float* __restrict__ Uw,
    const float* __restrict__ Vb, const float* __restrict__ Ub,
    const float* __restrict__ ww, const float* __restrict__ wb,
    float* __restrict__ wsAcc, float* __restrict__ wsM, float* __restrict__ wsS,
    int nb, int nTiles)
{
  __shared__ __align__(16) unsigned short xt[TILE_R * NUM_IN]; // 32 KB bf16 tile (XOR-swizzled)
  __shared__ float prered[TILE_R][2][64];                      // 8 KB per-K-half pre-activations
  __shared__ float lgs[TILE_R];

  const int tid = threadIdx.x;
  const int b   = blockIdx.x;
  const int w   = tid >> 6;
  const int l   = tid & 63;
  const int l15 = l & 15;
  const int kg  = l >> 4;
  char* xbase = (char*)xt;

  const bool isCons = (w < 8);
  const int nt = w & 3;
  const int kh = (w >> 2) & 1;

  const int h = tid & 31;
  float vbh = 0.f, ubh = 0.f, wwh = 0.f;
  if (tid < 512) { vbh = Vb[h]; ubh = Ub[h]; wwh = ww[h]; }
  const float wb0 = wb[0];

  // ---- consumer: load this wave's bf16 weight fragments once (64 VGPRs) ----
  // B[k][n]: lane holds col o = nt*16 + (l&15); k = kh*512 + s*32 + (l>>4)*8 + i
  uint4 bfr[16];
  if (isCons) {
    const int o = (nt << 4) + l15;
    const float* Wr = (o < 32) ? (Vw + (size_t)o * NUM_IN) : (Uw + (size_t)(o - 32) * NUM_IN);
    #pragma unroll
    for (int s = 0; s < 16; ++s) {
      const int k0 = (kh << 9) + (s << 5) + (kg << 3);
      const float4 a = *reinterpret_cast<const float4*>(Wr + k0);
      const float4 c = *reinterpret_cast<const float4*>(Wr + k0 + 4);
      uint4 v;
      v.x = pk2(a.x, a.y); v.y = pk2(a.z, a.w);
      v.z = pk2(c.x, c.y); v.w = pk2(c.z, c.w);
      bfr[s] = v;
    }
  }

  // ---- producer constants ----
  const int ptid  = tid - 512;          // 0..255
  const int srow  = ptid >> 4;          // row this thread stages
  const int scolb = (ptid & 15) << 7;   // byte col base within row

  float4 stg[16];
  float M = -INFINITY, S = 0.f;
  float2 accB = make_float2(0.f, 0.f);

  int T = b;
  // prologue: stage first tile
  if (!isCons) {
    const float4* src = reinterpret_cast<const float4*>(x + (size_t)T * (TILE_R * NUM_IN)) + (ptid << 4);
    #pragma unroll
    for (int j = 0; j < 16; ++j) stg[j] = src[j];
    #pragma unroll
    for (int jj = 0; jj < 8; ++jj) {
      const float4 a = stg[2*jj], c = stg[2*jj+1];
      uint4 v;
      v.x = pk2(a.x, a.y); v.y = pk2(a.z, a.w);
      v.z = pk2(c.x, c.y); v.w = pk2(c.z, c.w);
      int addr = (srow << 11) + scolb + (jj << 4);
      addr ^= (srow & 7) << 4;
      *reinterpret_cast<uint4*>(xbase + addr) = v;
    }
  }
  BARX();

  while (true) {
    const bool more = (T + nb) < nTiles;

    if (!isCons) {
      if (more) {  // issue next tile's loads early; latency hides under compute
        const float4* src = reinterpret_cast<const float4*>(x + (size_t)(T + nb) * (TILE_R * NUM_IN)) + (ptid << 4);
        #pragma unroll
        for (int j = 0; j < 16; ++j) stg[j] = src[j];
      }
    } else {
      // logits partial over this wave's K-half: 16 MFMAs
      f32x4 acc = {0.f, 0.f, 0.f, 0.f};
      #pragma unroll
      for (int s = 0; s < 16; ++s) {
        const int aaddr = (l15 << 11) + ((((kh << 10) + (s << 6) + (kg << 4))) ^ ((l15 & 7) << 4));
        const bf16x8 af  = *reinterpret_cast<const bf16x8*>(xbase + aaddr);
        const bf16x8 bfv = __builtin_bit_cast(bf16x8, bfr[s]);
        acc = __builtin_amdgcn_mfma_f32_16x16x32_bf16(af, bfv, acc, 0, 0, 0);
      }
      // C/D layout: row = (l>>4)*4 + reg, col = l&15  [guide-verified]
      #pragma unroll
      for (int r = 0; r < 4; ++r)
        prered[(kg << 2) + r][kh][(nt << 4) + l15] = acc[r];
    }
    BARX();  // (A) partial pre-acts visible

    if (tid < 512) {  // activations + per-row logit
      const int r = (tid >> 5) & 15;
      const float pv = prered[r][0][h] + prered[r][1][h] + vbh;
      const float pu = prered[r][0][32 + h] + prered[r][1][32 + h] + ubh;
      const float av = tanhf(pv);
      const float au = 1.f / (1.f + __expf(-pu));
      float g = av * au * wwh;
      g += __shfl_xor(g, 1);
      g += __shfl_xor(g, 2);
      g += __shfl_xor(g, 4);
      g += __shfl_xor(g, 8);
      g += __shfl_xor(g, 16);
      if (h == 0) lgs[r] = g + wb0;
    }
    BARX();  // (C) logits visible

    if (isCons) {  // Phase B: online softmax + weighted accumulation (2 cols/lane)
      float lgv[16];
      #pragma unroll
      for (int r = 0; r < 16; ++r) lgv[r] = lgs[r];
      float mc = lgv[0];
      #pragma unroll
      for (int r = 1; r < 16; ++r) mc = fmaxf(mc, lgv[r]);
      const float newM = fmaxf(M, mc);
      const float scale = __expf(M - newM);
      S *= scale; accB.x *= scale; accB.y *= scale;
      #pragma unroll
      for (int r = 0; r < 16; ++r) {
        const float p = __expf(lgv[r] - newM);
        S += p;
        const int baddr = (r << 11) + ((((w << 8) + (l << 2))) ^ ((r & 7) << 4));
        const unsigned int xb = *reinterpret_cast<const unsigned int*>(xbase + baddr);
        accB.x += p * bf2f(xb & 0xffffu);
        accB.y += p * bf2f(xb >> 16);
      }
      M = newM;
    }
    BARX();  // (D1) xt free

    if (!isCons && more) {  // write next tile (loads have arrived by now)
      #pragma unroll
      for (int jj = 0; jj < 8; ++jj) {
        const float4 a = stg[2*jj], c = stg[2*jj+1];
        uint4 v;
        v.x = pk2(a.x, a.y); v.y = pk2(a.z, a.w);
        v.z = pk2(c.x, c.y); v.w = pk2(c.z, c.w);
        int addr = (srow << 11) + scolb + (jj << 4);
        addr ^= (srow & 7) << 4;
        *reinterpret_cast<uint4*>(xbase + addr) = v;
      }
    }
    BARX();  // (D2) new tile visible

    if (!more) break;
    T += nb;
  }

  if (isCons) {
    float2* dst = reinterpret_cast<float2*>(&wsAcc[(size_t)b * NUM_IN + (w << 7) + (l << 1)]);
    *dst = accB;
    if (tid == 0) { wsM[b] = M; wsS[b] = S; }
  }
}

__global__ void ga_combine(const float* __restrict__ wsAcc, const float* __restrict__ wsM,
                           const float* __restrict__ wsS, float* __restrict__ out, int nb)
{
  const int e = blockIdx.x * blockDim.x + threadIdx.x;
  if (e >= NUM_IN) return;
  float M = -INFINITY;
  for (int i = 0; i < nb; ++i) M = fmaxf(M, wsM[i]);
  float S = 0.f, m = 0.f;
  for (int i = 0; i < nb; ++i) {
    const float wg = __expf(wsM[i] - M);
    S += wg * wsS[i];
    m = fmaf(wg, wsAcc[(size_t)i * NUM_IN + e], m);
  }
  out[e] = m / S;
}

extern "C" void kernel_launch(void* const* d_in, const int* in_sizes, int n_in,
                              void* d_out, int out_size, void* d_ws, size_t ws_size,
                              hipStream_t stream)
{
  const float* x  = (const float*)d_in[0];
  const float* Vw = (const float*)d_in[1];
  const float* Vb = (const float*)d_in[2];
  const float* Uw = (const float*)d_in[3];
  const float* Ub = (const float*)d_in[4];
  const float* ww = (const float*)d_in[5];
  const float* wb = (const float*)d_in[6];
  float* out = (float*)d_out;

  const int Nrows  = in_sizes[0] / NUM_IN;   // 200000
  const int nTiles = Nrows / TILE_R;         // 12500

  const size_t per = (size_t)NUM_IN * 4 + 8;
  int nb = (int)(ws_size / per);
  if (nb > NB_MAX)  nb = NB_MAX;
  if (nb > nTiles)  nb = nTiles;
  if (nb < 1)       nb = 1;

  float* wsAcc = (float*)d_ws;
  float* wsM   = wsAcc + (size_t)nb * NUM_IN;
  float* wsS   = wsM + nb;

  ga_main<<<nb, 768, 0, stream>>>(x, Vw, Uw, Vb, Ub, ww, wb, wsAcc, wsM, wsS, nb, nTiles);
  ga_combine<<<4, 256, 0, stream>>>(wsAcc, wsM, wsS, out, nb);
}

// Round 4
// 237.817 us; speedup vs baseline: 3.7510x; 3.7510x over previous
//
#include <hip/hip_runtime.h>
#include <math.h>

#define NUM_IN 1024
#define TILE_R 16
#define NB_MAX 256

using bf16x8 = __attribute__((ext_vector_type(8))) short;
using f32x4  = __attribute__((ext_vector_type(4))) float;

typedef __attribute__((address_space(1))) const void gvoid_t;
typedef __attribute__((address_space(3))) void lvoid_t;

__device__ __forceinline__ unsigned int f2bf1(float f) {
  unsigned int u = __float_as_uint(f);
  return (u + 0x7fffu + ((u >> 16) & 1u)) >> 16;   // RNE f32 -> bf16
}
__device__ __forceinline__ unsigned int pk2(float a, float b) {
  return f2bf1(a) | (f2bf1(b) << 16);
}
__device__ __forceinline__ float bf2f(unsigned int s) {
  return __uint_as_float(s << 16);
}

// barrier draining LDS ops only — global/DMA traffic stays in flight
#define BARX() do { \
  __builtin_amdgcn_sched_barrier(0); \
  asm volatile("s_waitcnt lgkmcnt(0)" ::: "memory"); \
  __builtin_amdgcn_s_barrier(); \
  __builtin_amdgcn_sched_barrier(0); \
} while (0)

#define WAIT_VM0() do { \
  __builtin_amdgcn_sched_barrier(0); \
  asm volatile("s_waitcnt vmcnt(0)" ::: "memory"); \
  __builtin_amdgcn_sched_barrier(0); \
} while (0)

// 256 blocks x 512 threads (8 waves, homogeneous). Wave w: n-tile nt=w&3,
// K-half kh=w>>2. Tile = 16 rows x 1024. f32 DMA-landing buffer + swizzled
// bf16 double buffer. Weights register-resident (64 VGPR), anchored per-component.
__global__ __launch_bounds__(512, 1) void ga_main(
    const float* __restrict__ x,
    const float* __restrict__ Vw, const float* __restrict__ Uw,
    const float* __restrict__ Vb, const float* __restrict__ Ub,
    const float* __restrict__ ww, const float* __restrict__ wb,
    float* __restrict__ wsAcc, float* __restrict__ wsM, float* __restrict__ wsS,
    int nb, int nTiles)
{
  __shared__ __align__(16) unsigned short xt[2][TILE_R * NUM_IN]; // 64 KB bf16 dbuf (XOR-swizzled)
  __shared__ __align__(16) float fstg[TILE_R * NUM_IN];           // 64 KB f32 DMA landing (linear)
  __shared__ __align__(16) float prered[TILE_R][2][64];           // 8 KB
  __shared__ __align__(16) float lgs[TILE_R];

  const int tid = threadIdx.x;
  const int b   = blockIdx.x;
  const int w   = tid >> 6;
  const int l   = tid & 63;
  const int l15 = l & 15;
  const int kg  = l >> 4;
  const int nt  = w & 3;
  const int kh  = w >> 2;
  const int h   = tid & 31;
  const int rr  = tid >> 5;

  const float vbh = Vb[h], ubh = Ub[h], wwh = ww[h];
  const float wb0 = wb[0];

  // ---- weights: bf16 B-fragments, 16 x uint4 = 64 VGPR, loaded once ----
  // lane holds col o = nt*16 + l15; k = kh*512 + s*32 + kg*8 + i
  uint4 bfr[16];
  {
    const int o = (nt << 4) + l15;
    const float* Wr = (o < 32) ? (Vw + (size_t)o * NUM_IN) : (Uw + (size_t)(o - 32) * NUM_IN);
    #pragma unroll
    for (int s = 0; s < 16; ++s) {
      const int k0 = (kh << 9) + (s << 5) + (kg << 3);
      const float4 a = *reinterpret_cast<const float4*>(Wr + k0);
      const float4 c = *reinterpret_cast<const float4*>(Wr + k0 + 4);
      uint4 v;
      v.x = pk2(a.x, a.y); v.y = pk2(a.z, a.w);
      v.z = pk2(c.x, c.y); v.w = pk2(c.z, c.w);
      bfr[s] = v;
    }
    // anchor: 32-bit tied constraints (128-bit "+v" is unsupported); forces the
    // weight block to stay materialized in VGPRs instead of re-loading per tile
    #pragma unroll
    for (int s = 0; s < 16; ++s)
      asm volatile("" : "+v"(bfr[s].x), "+v"(bfr[s].y), "+v"(bfr[s].z), "+v"(bfr[s].w));
  }

  const char* xbytes = (const char*)x;
  char* fstgb = (char*)fstg;

  float M = -INFINITY, S = 0.f;
  float aX = 0.f, aY = 0.f;
  const int cb = (w << 8) + (l << 2);    // Phase-B byte col base
  int cur = 0;
  int T = b;

  // ---- prologue: DMA tile b -> fstg, convert -> xt[0] ----
  {
    const char* gsrc = xbytes + (size_t)T * (TILE_R * NUM_IN * 4) + (w << 13) + (l << 4);
    #pragma unroll
    for (int j = 0; j < 8; ++j)
      __builtin_amdgcn_global_load_lds((gvoid_t*)(gsrc + (j << 10)),
                                       (lvoid_t*)(fstgb + (w << 13) + (j << 10)), 16, 0, 0);
  }
  WAIT_VM0();
  {
    const f32x4* fs = (const f32x4*)fstg;
    char* xb = (char*)xt[0];
    #pragma unroll
    for (int j = 0; j < 8; ++j) {
      const int q = (w << 9) + (j << 6) + l;     // float4 index, own DMA region
      const f32x4 f = fs[q];
      const int row = q >> 8;
      uint2 v; v.x = pk2(f[0], f[1]); v.y = pk2(f[2], f[3]);
      *reinterpret_cast<uint2*>(xb + (((q << 3)) ^ ((row & 7) << 4))) = v;
    }
  }
  BARX();

  while (true) {
    const bool more = (T + nb) < nTiles;

    // ---- issue next tile's DMA early (hides under whole iteration) ----
    if (more) {
      const char* gsrc = xbytes + (size_t)(T + nb) * (TILE_R * NUM_IN * 4) + (w << 13) + (l << 4);
      #pragma unroll
      for (int j = 0; j < 8; ++j)
        __builtin_amdgcn_global_load_lds((gvoid_t*)(gsrc + (j << 10)),
                                         (lvoid_t*)(fstgb + (w << 13) + (j << 10)), 16, 0, 0);
    }

    // ---- MFMA: partial logits for this wave's (nt, kh) ----
    {
      f32x4 acc = {0.f, 0.f, 0.f, 0.f};
      const char* xb = (const char*)xt[cur];
      #pragma unroll
      for (int s = 0; s < 16; ++s) {
        const int aoff = (l15 << 11) + ((((kh << 10) + (s << 6) + (kg << 4))) ^ ((l15 & 7) << 4));
        const bf16x8 af = *reinterpret_cast<const bf16x8*>(xb + aoff);
        acc = __builtin_amdgcn_mfma_f32_16x16x32_bf16(af, __builtin_bit_cast(bf16x8, bfr[s]), acc, 0, 0, 0);
      }
      #pragma unroll
      for (int r = 0; r < 4; ++r)
        prered[(kg << 2) + r][kh][(nt << 4) + l15] = acc[r];   // C/D: row=(l>>4)*4+r, col=l15
    }
    BARX();

    // ---- activations + per-row logit (512 threads = 16 rows x 32 h) ----
    {
      const float pv = prered[rr][0][h] + prered[rr][1][h] + vbh;
      const float pu = prered[rr][0][32 + h] + prered[rr][1][32 + h] + ubh;
      const float av = tanhf(pv);
      const float au = 1.f / (1.f + __expf(-pu));
      float g = av * au * wwh;
      g += __shfl_xor(g, 1);
      g += __shfl_xor(g, 2);
      g += __shfl_xor(g, 4);
      g += __shfl_xor(g, 8);
      g += __shfl_xor(g, 16);
      if (h == 0) lgs[rr] = g + wb0;
    }
    BARX();

    // ---- Phase B: online softmax + weighted accumulation (2 cols/thread) ----
    {
      const f32x4* lgv = (const f32x4*)lgs;
      float lf[16];
      #pragma unroll
      for (int p4 = 0; p4 < 4; ++p4) {
        const f32x4 v = lgv[p4];
        lf[p4*4+0] = v[0]; lf[p4*4+1] = v[1]; lf[p4*4+2] = v[2]; lf[p4*4+3] = v[3];
      }
      float mc = lf[0];
      #pragma unroll
      for (int r = 1; r < 16; ++r) mc = fmaxf(mc, lf[r]);
      const float newM = fmaxf(M, mc);
      const float scale = __expf(M - newM);
      S *= scale; aX *= scale; aY *= scale;
      const char* xb = (const char*)xt[cur];
      #pragma unroll
      for (int r = 0; r < 16; ++r) {
        const float p = __expf(lf[r] - newM);
        S += p;
        const unsigned int xv = *reinterpret_cast<const unsigned int*>(
            xb + (r << 11) + (cb ^ ((r & 7) << 4)));
        aX += p * bf2f(xv & 0xffffu);
        aY += p * bf2f(xv >> 16);
      }
      M = newM;
    }

    // ---- convert own DMA region f32 -> swizzled bf16 into other buffer ----
    if (more) {
      WAIT_VM0();   // own-wave DMA landed (issued a full compute-phase ago)
      const f32x4* fs = (const f32x4*)fstg;
      char* xb = (char*)xt[cur ^ 1];
      #pragma unroll
      for (int j = 0; j < 8; ++j) {
        const int q = (w << 9) + (j << 6) + l;
        const f32x4 f = fs[q];
        const int row = q >> 8;
        uint2 v; v.x = pk2(f[0], f[1]); v.y = pk2(f[2], f[3]);
        *reinterpret_cast<uint2*>(xb + (((q << 3)) ^ ((row & 7) << 4))) = v;
      }
    }
    BARX();

    if (!more) break;
    cur ^= 1;
    T += nb;
  }

  float2* dst = reinterpret_cast<float2*>(&wsAcc[(size_t)b * NUM_IN + (w << 7) + (l << 1)]);
  *dst = make_float2(aX, aY);
  if (tid == 0) { wsM[b] = M; wsS[b] = S; }
}

__global__ void ga_combine(const float* __restrict__ wsAcc, const float* __restrict__ wsM,
                           const float* __restrict__ wsS, float* __restrict__ out, int nb)
{
  const int e = blockIdx.x * blockDim.x + threadIdx.x;
  if (e >= NUM_IN) return;
  float M = -INFINITY;
  for (int i = 0; i < nb; ++i) M = fmaxf(M, wsM[i]);
  float S = 0.f, m = 0.f;
  for (int i = 0; i < nb; ++i) {
    const float wg = __expf(wsM[i] - M);
    S += wg * wsS[i];
    m = fmaf(wg, wsAcc[(size_t)i * NUM_IN + e], m);
  }
  out[e] = m / S;
}

extern "C" void kernel_launch(void* const* d_in, const int* in_sizes, int n_in,
                              void* d_out, int out_size, void* d_ws, size_t ws_size,
                              hipStream_t stream)
{
  const float* x  = (const float*)d_in[0];
  const float* Vw = (const float*)d_in[1];
  const float* Vb = (const float*)d_in[2];
  const float* Uw = (const float*)d_in[3];
  const float* Ub = (const float*)d_in[4];
  const float* ww = (const float*)d_in[5];
  const float* wb = (const float*)d_in[6];
  float* out = (float*)d_out;

  const int Nrows  = in_sizes[0] / NUM_IN;   // 200000
  const int nTiles = Nrows / TILE_R;         // 12500

  const size_t per = (size_t)NUM_IN * 4 + 8;
  int nb = (int)(ws_size / per);
  if (nb > NB_MAX)  nb = NB_MAX;
  if (nb > nTiles)  nb = nTiles;
  if (nb < 1)       nb = 1;

  float* wsAcc = (float*)d_ws;
  float* wsM   = wsAcc + (size_t)nb * NUM_IN;
  float* wsS   = wsM + nb;

  ga_main<<<nb, 512, 0, stream>>>(x, Vw, Uw, Vb, Ub, ww, wb, wsAcc, wsM, wsS, nb, nTiles);
  ga_combine<<<4, 256, 0, stream>>>(wsAcc, wsM, wsS, out, nb);
}